// Round 15
// baseline (117.254 us; speedup 1.0000x reference)
//
#include <hip/hip_runtime.h>
#include <hip/hip_bf16.h>
#include <math.h>

typedef __bf16 bf16x8 __attribute__((ext_vector_type(8)));
typedef float f32x4 __attribute__((ext_vector_type(4)));

namespace {
constexpr int B  = 4;
constexpr int T  = 2048;
constexpr int C  = 512;
constexpr int H  = 8;
constexpr int Dh = 64;
constexpr int R  = 16;
constexpr int Nr = 128;   // T / R
constexpr int K  = 8;     // top-k regions
constexpr int BT = B * T;        // 8192
constexpr int QKV_N = 3 * C;     // 1536
constexpr int KD = 512;          // GEMM inner depth (= C)
constexpr float SCALE = 0.125f;  // 1/sqrt(Dh)
}

static __device__ __forceinline__ unsigned short f2bf(float f) {
  unsigned int u = __float_as_uint(f);
  u += 0x7fffu + ((u >> 16) & 1u);   // RNE
  return (unsigned short)(u >> 16);
}

static __device__ __forceinline__ unsigned cvt_pk_bf16(float lo, float hi) {
  unsigned r;
  asm("v_cvt_pk_bf16_f32 %0, %1, %2" : "=v"(r) : "v"(lo), "v"(hi));
  return r;
}

static __device__ __forceinline__ void gload16(const unsigned short* g, unsigned short* l) {
  __builtin_amdgcn_global_load_lds(
      (const __attribute__((address_space(1))) unsigned int*)g,
      (__attribute__((address_space(3))) unsigned int*)l, 16, 0, 0);
}

// order-preserving f32 -> u32 key (max-compatible, no NaN expected)
static __device__ __forceinline__ unsigned fkey(float f) {
  unsigned u = __float_as_uint(f);
  return (u & 0x80000000u) ? ~u : (u ^ 0x80000000u);
}

// ---------------------------------------------------------------------------
// prep_combo (R6-exact): blocks 0..767 transpose Wqkv, 768..1023 Wout,
// 1024..1279 convert x->bf16 + region means (selection-safe order).
// ---------------------------------------------------------------------------
__global__ __launch_bounds__(256) void prep_combo_kernel(
    const float* __restrict__ x, const float* __restrict__ Wqkv,
    const float* __restrict__ Wout,
    unsigned short* __restrict__ xbf, float* __restrict__ xavg,
    unsigned short* __restrict__ wqkvt, unsigned short* __restrict__ woutt) {
  int id = blockIdx.x;
  if (id >= 1024) {
    const int rid = (id - 1024) * 2 + (threadIdx.x >> 7);  // region 0..511
    const int c4 = threadIdx.x & 127;
    const float4* xp = (const float4*)(x + (size_t)rid * R * C) + c4;
    ushort4* xb = (ushort4*)(xbf + (size_t)rid * R * C) + c4;
    float sx = 0.f, sy = 0.f, sz = 0.f, sw = 0.f;
#pragma unroll
    for (int r = 0; r < R; ++r) {
      const float4 v = xp[(size_t)r * 128];
      ushort4 o;
      o.x = f2bf(v.x); o.y = f2bf(v.y); o.z = f2bf(v.z); o.w = f2bf(v.w);
      xb[(size_t)r * 128] = o;
      sx += v.x; sy += v.y; sz += v.z; sw += v.w;
    }
    float4 av; av.x = sx * 0.0625f; av.y = sy * 0.0625f;
    av.z = sz * 0.0625f; av.w = sw * 0.0625f;
    *((float4*)(xavg + (size_t)rid * C) + c4) = av;
    return;
  }
  __shared__ float tile[32][33];
  const float* W; unsigned short* Wt; int Nd, n0, k0;
  if (id < 768) { W = Wqkv; Wt = wqkvt; Nd = QKV_N; n0 = (id % 48) * 32; k0 = (id / 48) * 32; }
  else { id -= 768; W = Wout; Wt = woutt; Nd = C; n0 = (id % 16) * 32; k0 = (id / 16) * 32; }
  const int tx = threadIdx.x & 31, ty = threadIdx.x >> 5;   // ty 0..7
#pragma unroll
  for (int i = 0; i < 32; i += 8)
    tile[ty + i][tx] = W[(size_t)(k0 + ty + i) * Nd + (n0 + tx)];
  __syncthreads();
#pragma unroll
  for (int i = 0; i < 32; i += 8)
    Wt[(size_t)(n0 + ty + i) * KD + (k0 + tx)] = f2bf(tile[tx][ty + i]);
}

// ---------------------------------------------------------------------------
// R6-proven 4-wave mainloop: 128x128 tile, BK=32. FROZEN — do not modify.
// ---------------------------------------------------------------------------
__device__ __forceinline__ void mfma_mainloop(
    const unsigned short* __restrict__ A, const unsigned short* __restrict__ Bt,
    int bm, int bn, unsigned short* As, unsigned short* Bs, f32x4 (&acc)[4][4]) {
  const int tid = threadIdx.x;
  const int wave = tid >> 6, lane = tid & 63;
  const int wr = wave >> 1, wc = wave & 1;
  const unsigned short* ga = A  + (size_t)(bm + wave * 16 + (lane >> 2)) * KD + (lane & 3) * 8;
  const unsigned short* gb = Bt + (size_t)(bn + wave * 16 + (lane >> 2)) * KD + (lane & 3) * 8;
  unsigned short* lA = As + wave * 512;
  unsigned short* lB = Bs + wave * 512;
  const int fr = lane & 15, kg = lane >> 4;
  const unsigned short* rA = As + (wr * 64 + fr) * 32 + kg * 8;
  const unsigned short* rB = Bs + (wc * 64 + fr) * 32 + kg * 8;
  for (int k0 = 0; k0 < KD; k0 += 32) {
    gload16(ga + k0,                    lA);
    gload16(ga + (size_t)64 * KD + k0,  lA + 2048);
    gload16(gb + k0,                    lB);
    gload16(gb + (size_t)64 * KD + k0,  lB + 2048);
    __syncthreads();
    bf16x8 a[4], b[4];
#pragma unroll
    for (int m = 0; m < 4; ++m) a[m] = *(const bf16x8*)(rA + m * 512);
#pragma unroll
    for (int n = 0; n < 4; ++n) b[n] = *(const bf16x8*)(rB + n * 512);
#pragma unroll
    for (int m = 0; m < 4; ++m)
#pragma unroll
      for (int n = 0; n < 4; ++n)
        acc[m][n] = __builtin_amdgcn_mfma_f32_16x16x32_bf16(a[m], b[n], acc[m][n], 0, 0, 0);
    __syncthreads();
  }
}

// ---------------------------------------------------------------------------
// Mega GEMM (R10-exact, FROZEN): blocks 0..767 = bf16-MFMA QKV GEMM;
// 768..1023 = f32 qkavg GEMM (selection-critical, unchanged arithmetic).
// ---------------------------------------------------------------------------
__global__ __launch_bounds__(256) void mega_gemm_kernel(
    const unsigned short* __restrict__ xbf, const unsigned short* __restrict__ Wt,
    const float* __restrict__ bqkv,
    unsigned short* __restrict__ qbf, unsigned short* __restrict__ kbf,
    unsigned short* __restrict__ vt,
    const float* __restrict__ xavg, const float* __restrict__ Wqkv,
    float* __restrict__ qavg, float* __restrict__ kavg) {
  __shared__ unsigned short SMEM[2 * 128 * 32];   // 16 KB, carved per path
  const int gid = blockIdx.x;
  const int tid = threadIdx.x;
  if (gid < 768) {
    unsigned short* As = SMEM;
    unsigned short* Bs = SMEM + 128 * 32;
    f32x4 acc[4][4] = {};
    const int id = (gid & 7) * 96 + (gid >> 3);   // XCD-chunked swizzle
    const int bn = (id % 12) * 128, bm = (id / 12) * 128;
    mfma_mainloop(xbf, Wt, bm, bn, As, Bs, acc);
    const int lane = tid & 63, wave = tid >> 6;
    const int wr = wave >> 1, wc = wave & 1;
    const int scol = bn + wc * 64;           // 64-aligned -> s,h uniform per wave
    const int s = scol >> 9, h = (scol >> 6) & 7;
    const int b = bm >> 11, t0b = (bm & (T - 1)) + wr * 64;
    const int bh = b * H + h;
    if (s == 2) {
#pragma unroll
      for (int n = 0; n < 4; ++n) {
        const int d = (n * 16 + (lane & 15));
        const float bv = bqkv[scol + n * 16 + (lane & 15)];
#pragma unroll
        for (int m = 0; m < 4; ++m) {
          const int t = t0b + m * 16 + (lane >> 4) * 4;
          ushort4 pk;
          pk.x = f2bf(acc[m][n][0] + bv); pk.y = f2bf(acc[m][n][1] + bv);
          pk.z = f2bf(acc[m][n][2] + bv); pk.w = f2bf(acc[m][n][3] + bv);
          *(ushort4*)&vt[((size_t)bh * Dh + d) * T + t] = pk;
        }
      }
    } else {
      unsigned short* dstbase = ((s == 0) ? qbf : kbf) + (size_t)bh * T * Dh;
      const int g = lane >> 4, i = lane & 3, a = (lane >> 2) & 3;
#pragma unroll
      for (int n = 0; n < 4; ++n) {
        const float bv = bqkv[scol + n * 16 + (lane & 15)];
#pragma unroll
        for (int m = 0; m < 4; ++m) {
          const float v0 = acc[m][n][0] + bv, v1 = acc[m][n][1] + bv;
          const float v2 = acc[m][n][2] + bv, v3 = acc[m][n][3] + bv;
          const unsigned p01 = cvt_pk_bf16(v0, v1);
          const unsigned p23 = cvt_pk_bf16(v2, v3);
          const unsigned u01 = (unsigned)__shfl_xor((int)p01, 1);
          const unsigned u23 = (unsigned)__shfl_xor((int)p23, 1);
          const unsigned A  = (lane & 1) ? ((u01 >> 16) | (p01 & 0xFFFF0000u))
                                         : ((p01 & 0xFFFFu) | (u01 << 16));
          const unsigned Bb = (lane & 1) ? ((u23 >> 16) | (p23 & 0xFFFF0000u))
                                         : ((p23 & 0xFFFFu) | (u23 << 16));
          const unsigned w  = (unsigned)__shfl_xor((int)A, 2);
          const unsigned xw = (unsigned)__shfl_xor((int)Bb, 2);
          uint2 res;
          res.x = (lane & 2) ? xw : A;
          res.y = (lane & 2) ? Bb : w;
          const int t = t0b + m * 16 + 4 * g + i;
          const int d = n * 16 + 4 * a;
          *(uint2*)&dstbase[(size_t)t * Dh + d] = res;
        }
      }
    }
  } else {
    // ---- qkavg path (R6-exact): 32x64 f32 tile, BK=32, 4x2 microtile ----
    float* Asf = (float*)SMEM;            // [32][36] k-major (transposed store)
    float* Bsf = (float*)SMEM + 32 * 36;  // [32][68]
    const int id2 = gid - 768;
    const int bm = (id2 >> 4) * 32, bn = (id2 & 15) * 64;
    const int arow = tid >> 3;            // 0..31
    const int acol = (tid & 7) << 2;      // 0..28
    const int brow = tid >> 4;            // 0..15 (+16)
    const int bcol = (tid & 15) << 2;     // 0..60
    const int tm = (tid >> 5) << 2;       // 0..28
    const int tn = (tid & 31) << 1;       // 0..62
    float acc[4][2] = {};
    for (int k0 = 0; k0 < KD; k0 += 32) {
      const float4 a = *(const float4*)&xavg[(size_t)(bm + arow) * KD + (k0 + acol)];
      Asf[(acol + 0) * 36 + arow] = a.x;
      Asf[(acol + 1) * 36 + arow] = a.y;
      Asf[(acol + 2) * 36 + arow] = a.z;
      Asf[(acol + 3) * 36 + arow] = a.w;
#pragma unroll
      for (int p = 0; p < 2; ++p)
        *(float4*)&Bsf[(brow + 16 * p) * 68 + bcol] =
            *(const float4*)&Wqkv[(size_t)(k0 + brow + 16 * p) * QKV_N + (bn + bcol)];
      __syncthreads();
#pragma unroll
      for (int kk = 0; kk < 32; ++kk) {
        const float4 av = *(const float4*)&Asf[kk * 36 + tm];
        const float2 bv = *(const float2*)&Bsf[kk * 68 + tn];
        const float aa[4] = {av.x, av.y, av.z, av.w};
#pragma unroll
        for (int i = 0; i < 4; ++i) {
          acc[i][0] += aa[i] * bv.x;
          acc[i][1] += aa[i] * bv.y;
        }
      }
      __syncthreads();
    }
#pragma unroll
    for (int i = 0; i < 4; ++i) {
      const int m = bm + tm + i;
      const int b = m >> 7, n = m & (Nr - 1);
#pragma unroll
      for (int j = 0; j < 2; ++j) {
        const int col = bn + tn + j;
        const int half = col >> 9, h = (col >> 6) & 7, d = col & 63;
        float* dst = half ? kavg : qavg;
        dst[(((size_t)b * H + h) * Nr + n) * Dh + d] = acc[i][j] + bqkv[col];
      }
    }
  }
}

// ---------------------------------------------------------------------------
// MFMA block-sparse attention with INLINE top-k (R13-exact, green).
// ---------------------------------------------------------------------------
__global__ __launch_bounds__(256) void attn_mfma_kernel(
    const unsigned short* __restrict__ qbf, const unsigned short* __restrict__ kbf,
    const unsigned short* __restrict__ vt,
    const float* __restrict__ qavg, const float* __restrict__ kavg,
    unsigned short* __restrict__ aoutbf) {
  const int phys = blockIdx.x * 4 + (threadIdx.x >> 6);
  const int blk = (phys & 7) * 512 + (phys >> 3);
  const int bh = blk >> 7, n = blk & (Nr - 1);
  const int b = bh >> 3, h = bh & 7;
  const int lane = threadIdx.x & 63;

  // ---- inline top-8 region selection (identical arithmetic to topk_kernel) ----
  const float qv = qavg[(size_t)blk * Dh + lane];
  const float4* k0p = (const float4*)(kavg + ((size_t)bh * Nr + lane) * Dh);
  const float4* k1p = (const float4*)(kavg + ((size_t)bh * Nr + lane + 64) * Dh);
  float d0 = 0.f, d1 = 0.f;
#pragma unroll
  for (int j = 0; j < 16; ++j) {
    const float4 a = k0p[j];
    const float4 bq = k1p[j];
    const float q0 = __shfl(qv, 4 * j + 0);
    const float q1 = __shfl(qv, 4 * j + 1);
    const float q2 = __shfl(qv, 4 * j + 2);
    const float q3 = __shfl(qv, 4 * j + 3);
    d0 += q0 * a.x;  d0 += q1 * a.y;  d0 += q2 * a.z;  d0 += q3 * a.w;
    d1 += q0 * bq.x; d1 += q1 * bq.y; d1 += q2 * bq.z; d1 += q3 * bq.w;
  }
  float v0 = d0, v1 = d1;
  int myidx = 0;
#pragma unroll
  for (int j = 0; j < K; ++j) {
    const unsigned long long c0 =
        ((unsigned long long)fkey(v0) << 32) | (unsigned)(127 - lane);
    const unsigned long long c1 =
        ((unsigned long long)fkey(v1) << 32) | (unsigned)(63 - lane);
    unsigned long long c = (c0 > c1) ? c0 : c1;
#pragma unroll
    for (int off = 1; off < 64; off <<= 1) {
      const unsigned long long o = __shfl_xor(c, off);
      c = (o > c) ? o : c;
    }
    const int idx = 127 - (int)(c & 0xffffffffu);
    if (lane == j) myidx = idx;
    if (idx == lane) v0 = -INFINITY;
    if (idx == lane + 64) v1 = -INFINITY;
  }
  int ridx[8];
#pragma unroll
  for (int j = 0; j < 8; ++j) ridx[j] = __shfl(myidx, j);

  // ---- attention (R10-exact) ----
  const int q = lane & 15, kg = lane >> 4;
  const int kg1 = kg & 1, kgh = kg >> 1;
  const unsigned short* qp = qbf + ((size_t)bh * T + n * R + q) * Dh + kg * 8;
  const bf16x8 qf0 = *(const bf16x8*)(qp);
  const bf16x8 qf1 = *(const bf16x8*)(qp + 32);

  f32x4 s[8];
#pragma unroll
  for (int j = 0; j < 8; ++j) {
    const unsigned short* kp = kbf + ((size_t)bh * T + ridx[j] * R + q) * Dh + kg * 8;
    const bf16x8 kf0 = *(const bf16x8*)(kp);
    const bf16x8 kf1 = *(const bf16x8*)(kp + 32);
    f32x4 acc = {};
    acc = __builtin_amdgcn_mfma_f32_16x16x32_bf16(kf0, qf0, acc, 0, 0, 0);
    acc = __builtin_amdgcn_mfma_f32_16x16x32_bf16(kf1, qf1, acc, 0, 0, 0);
    s[j] = acc;
  }

  float mx = s[0][0];
#pragma unroll
  for (int j = 0; j < 8; ++j)
#pragma unroll
    for (int r = 0; r < 4; ++r) mx = fmaxf(mx, s[j][r]);
  mx = fmaxf(mx, __shfl_xor(mx, 16));
  mx = fmaxf(mx, __shfl_xor(mx, 32));
  float sum = 0.f;
#pragma unroll
  for (int j = 0; j < 8; ++j)
#pragma unroll
    for (int r = 0; r < 4; ++r) {
      const float e = __expf((s[j][r] - mx) * SCALE);
      s[j][r] = e; sum += e;
    }
  sum += __shfl_xor(sum, 16);
  sum += __shfl_xor(sum, 32);

  unsigned pk0[8], pk1[8];
#pragma unroll
  for (int j = 0; j < 8; ++j) {
    pk0[j] = cvt_pk_bf16(s[j][0], s[j][1]);
    pk1[j] = cvt_pk_bf16(s[j][2], s[j][3]);
  }

  const int srcA = kg1 * 32 + q;
  const int srcB = kg1 * 32 + 16 + q;
  f32x4 o[4] = {};
#pragma unroll
  for (int t = 0; t < 4; ++t) {
    const unsigned aa0 = __shfl((int)pk0[2 * t], srcA), aa1 = __shfl((int)pk0[2 * t + 1], srcA);
    const unsigned ab0 = __shfl((int)pk1[2 * t], srcA), ab1 = __shfl((int)pk1[2 * t + 1], srcA);
    const unsigned ba0 = __shfl((int)pk0[2 * t], srcB), ba1 = __shfl((int)pk0[2 * t + 1], srcB);
    const unsigned bb0 = __shfl((int)pk1[2 * t], srcB), bb1 = __shfl((int)pk1[2 * t + 1], srcB);
    union { uint4 u; bf16x8 v; } bu;
    bu.u.x = kgh ? aa1 : aa0;
    bu.u.y = kgh ? ab1 : ab0;
    bu.u.z = kgh ? ba1 : ba0;
    bu.u.w = kgh ? bb1 : bb0;
    const int reg = kgh ? ridx[2 * t + 1] : ridx[2 * t];
    const size_t tok = (size_t)reg * R + kg1 * 8;
#pragma unroll
    for (int dt = 0; dt < 4; ++dt) {
      const bf16x8 af = *(const bf16x8*)(vt + ((size_t)bh * Dh + 16 * dt + q) * T + tok);
      o[dt] = __builtin_amdgcn_mfma_f32_16x16x32_bf16(af, bu.v, o[dt], 0, 0, 0);
    }
  }

  const float inv = 1.0f / sum;
  unsigned short* dst = aoutbf + ((size_t)b * T + n * R + q) * C + h * Dh;
#pragma unroll
  for (int dt = 0; dt < 4; ++dt) {
    const unsigned plo = cvt_pk_bf16(o[dt][0] * inv, o[dt][1] * inv);
    const unsigned phi = cvt_pk_bf16(o[dt][2] * inv, o[dt][3] * inv);
    uint2 st; st.x = plo; st.y = phi;
    *(uint2*)(dst + 16 * dt + kg * 4) = st;
  }
}

// ---------------------------------------------------------------------------
// Output GEMM (R6-exact, 4-wave mainloop, FROZEN).
// ---------------------------------------------------------------------------
__global__ __launch_bounds__(256) void out_gemm_mfma_kernel(
    const unsigned short* __restrict__ Abf, const unsigned short* __restrict__ Wt,
    const float* __restrict__ bias, float* __restrict__ out) {
  __shared__ unsigned short As[128 * 32];
  __shared__ unsigned short Bs[128 * 32];
  f32x4 acc[4][4] = {};
  const int id = (blockIdx.x & 7) * 32 + (blockIdx.x >> 3);
  const int bn = (id & 3) * 128, bm = (id >> 2) * 128;
  mfma_mainloop(Abf, Wt, bm, bn, As, Bs, acc);
  const int lane = threadIdx.x & 63, wave = threadIdx.x >> 6;
  const int wr = wave >> 1, wc = wave & 1;
#pragma unroll
  for (int n = 0; n < 4; ++n) {
    const int col = bn + wc * 64 + n * 16 + (lane & 15);
    const float bv = bias[col];
#pragma unroll
    for (int m = 0; m < 4; ++m) {
      const int row = bm + wr * 64 + m * 16 + (lane >> 4) * 4;
#pragma unroll
      for (int r = 0; r < 4; ++r)
        out[(size_t)(row + r) * C + col] = acc[m][n][r] + bv;
    }
  }
}

extern "C" void kernel_launch(void* const* d_in, const int* in_sizes, int n_in,
                              void* d_out, int out_size, void* d_ws, size_t ws_size,
                              hipStream_t stream) {
  const float* x    = (const float*)d_in[0];
  const float* Wqkv = (const float*)d_in[1];
  const float* bqkv = (const float*)d_in[2];
  const float* Wout = (const float*)d_in[3];
  const float* bout = (const float*)d_in[4];
  float* out = (float*)d_out;

  float* ws = (float*)d_ws;
  const size_t bhtd = (size_t)B * H * T * Dh;     // 4,194,304
  const size_t navg = (size_t)B * H * Nr * Dh;    // 262,144
  float* qavg = ws;
  float* kavg = qavg + navg;
  float* xavg = kavg + navg;                       // B*Nr*C
  unsigned short* qbf    = (unsigned short*)(xavg + navg);
  unsigned short* kbf    = qbf + bhtd;
  unsigned short* vt     = kbf + bhtd;
  unsigned short* xbf    = vt + bhtd;
  unsigned short* wqkvt  = xbf + bhtd;
  unsigned short* woutt  = wqkvt + (size_t)QKV_N * KD;
  unsigned short* aoutbf = woutt + (size_t)C * KD;

  prep_combo_kernel<<<1280, 256, 0, stream>>>(x, Wqkv, Wout, xbf, xavg, wqkvt, woutt);
  mega_gemm_kernel<<<1024, 256, 0, stream>>>(xbf, wqkvt, bqkv, qbf, kbf, vt,
                                             xavg, Wqkv, qavg, kavg);
  attn_mfma_kernel<<<B * H * Nr / 4, 256, 0, stream>>>(qbf, kbf, vt, qavg, kavg, aoutbf);
  out_gemm_mfma_kernel<<<C / 128 * (BT / 128), 256, 0, stream>>>(aoutbf, woutt, bout, out);
}

// Round 16
// 115.485 us; speedup vs baseline: 1.0153x; 1.0153x over previous
//
#include <hip/hip_runtime.h>
#include <hip/hip_bf16.h>
#include <math.h>

typedef __bf16 bf16x8 __attribute__((ext_vector_type(8)));
typedef float f32x4 __attribute__((ext_vector_type(4)));

namespace {
constexpr int B  = 4;
constexpr int T  = 2048;
constexpr int C  = 512;
constexpr int H  = 8;
constexpr int Dh = 64;
constexpr int R  = 16;
constexpr int Nr = 128;   // T / R
constexpr int K  = 8;     // top-k regions
constexpr int BT = B * T;        // 8192
constexpr int QKV_N = 3 * C;     // 1536
constexpr int KD = 512;          // GEMM inner depth (= C)
constexpr float SCALE = 0.125f;  // 1/sqrt(Dh)
}

static __device__ __forceinline__ unsigned short f2bf(float f) {
  unsigned int u = __float_as_uint(f);
  u += 0x7fffu + ((u >> 16) & 1u);   // RNE
  return (unsigned short)(u >> 16);
}

static __device__ __forceinline__ unsigned cvt_pk_bf16(float lo, float hi) {
  unsigned r;
  asm("v_cvt_pk_bf16_f32 %0, %1, %2" : "=v"(r) : "v"(lo), "v"(hi));
  return r;
}

static __device__ __forceinline__ void gload16(const unsigned short* g, unsigned short* l) {
  __builtin_amdgcn_global_load_lds(
      (const __attribute__((address_space(1))) unsigned int*)g,
      (__attribute__((address_space(3))) unsigned int*)l, 16, 0, 0);
}

// order-preserving f32 -> u32 key (max-compatible, no NaN expected)
static __device__ __forceinline__ unsigned fkey(float f) {
  unsigned u = __float_as_uint(f);
  return (u & 0x80000000u) ? ~u : (u ^ 0x80000000u);
}

// ---------------------------------------------------------------------------
// prep_combo (R6-exact): blocks 0..767 transpose Wqkv, 768..1023 Wout,
// 1024..1279 convert x->bf16 + region means (selection-safe order).
// ---------------------------------------------------------------------------
__global__ __launch_bounds__(256) void prep_combo_kernel(
    const float* __restrict__ x, const float* __restrict__ Wqkv,
    const float* __restrict__ Wout,
    unsigned short* __restrict__ xbf, float* __restrict__ xavg,
    unsigned short* __restrict__ wqkvt, unsigned short* __restrict__ woutt) {
  int id = blockIdx.x;
  if (id >= 1024) {
    const int rid = (id - 1024) * 2 + (threadIdx.x >> 7);  // region 0..511
    const int c4 = threadIdx.x & 127;
    const float4* xp = (const float4*)(x + (size_t)rid * R * C) + c4;
    ushort4* xb = (ushort4*)(xbf + (size_t)rid * R * C) + c4;
    float sx = 0.f, sy = 0.f, sz = 0.f, sw = 0.f;
#pragma unroll
    for (int r = 0; r < R; ++r) {
      const float4 v = xp[(size_t)r * 128];
      ushort4 o;
      o.x = f2bf(v.x); o.y = f2bf(v.y); o.z = f2bf(v.z); o.w = f2bf(v.w);
      xb[(size_t)r * 128] = o;
      sx += v.x; sy += v.y; sz += v.z; sw += v.w;
    }
    float4 av; av.x = sx * 0.0625f; av.y = sy * 0.0625f;
    av.z = sz * 0.0625f; av.w = sw * 0.0625f;
    *((float4*)(xavg + (size_t)rid * C) + c4) = av;
    return;
  }
  __shared__ float tile[32][33];
  const float* W; unsigned short* Wt; int Nd, n0, k0;
  if (id < 768) { W = Wqkv; Wt = wqkvt; Nd = QKV_N; n0 = (id % 48) * 32; k0 = (id / 48) * 32; }
  else { id -= 768; W = Wout; Wt = woutt; Nd = C; n0 = (id % 16) * 32; k0 = (id / 16) * 32; }
  const int tx = threadIdx.x & 31, ty = threadIdx.x >> 5;   // ty 0..7
#pragma unroll
  for (int i = 0; i < 32; i += 8)
    tile[ty + i][tx] = W[(size_t)(k0 + ty + i) * Nd + (n0 + tx)];
  __syncthreads();
#pragma unroll
  for (int i = 0; i < 32; i += 8)
    Wt[(size_t)(n0 + ty + i) * KD + (k0 + tx)] = f2bf(tile[tx][ty + i]);
}

// ---------------------------------------------------------------------------
// R6-proven 4-wave mainloop: 128x128 tile, BK=32. FROZEN — do not modify.
// ---------------------------------------------------------------------------
__device__ __forceinline__ void mfma_mainloop(
    const unsigned short* __restrict__ A, const unsigned short* __restrict__ Bt,
    int bm, int bn, unsigned short* As, unsigned short* Bs, f32x4 (&acc)[4][4]) {
  const int tid = threadIdx.x;
  const int wave = tid >> 6, lane = tid & 63;
  const int wr = wave >> 1, wc = wave & 1;
  const unsigned short* ga = A  + (size_t)(bm + wave * 16 + (lane >> 2)) * KD + (lane & 3) * 8;
  const unsigned short* gb = Bt + (size_t)(bn + wave * 16 + (lane >> 2)) * KD + (lane & 3) * 8;
  unsigned short* lA = As + wave * 512;
  unsigned short* lB = Bs + wave * 512;
  const int fr = lane & 15, kg = lane >> 4;
  const unsigned short* rA = As + (wr * 64 + fr) * 32 + kg * 8;
  const unsigned short* rB = Bs + (wc * 64 + fr) * 32 + kg * 8;
  for (int k0 = 0; k0 < KD; k0 += 32) {
    gload16(ga + k0,                    lA);
    gload16(ga + (size_t)64 * KD + k0,  lA + 2048);
    gload16(gb + k0,                    lB);
    gload16(gb + (size_t)64 * KD + k0,  lB + 2048);
    __syncthreads();
    bf16x8 a[4], b[4];
#pragma unroll
    for (int m = 0; m < 4; ++m) a[m] = *(const bf16x8*)(rA + m * 512);
#pragma unroll
    for (int n = 0; n < 4; ++n) b[n] = *(const bf16x8*)(rB + n * 512);
#pragma unroll
    for (int m = 0; m < 4; ++m)
#pragma unroll
      for (int n = 0; n < 4; ++n)
        acc[m][n] = __builtin_amdgcn_mfma_f32_16x16x32_bf16(a[m], b[n], acc[m][n], 0, 0, 0);
    __syncthreads();
  }
}

// ---------------------------------------------------------------------------
// Mega GEMM (R10-exact, FROZEN): blocks 0..767 = bf16-MFMA QKV GEMM;
// 768..1023 = f32 qkavg GEMM (selection-critical, unchanged arithmetic).
// ---------------------------------------------------------------------------
__global__ __launch_bounds__(256) void mega_gemm_kernel(
    const unsigned short* __restrict__ xbf, const unsigned short* __restrict__ Wt,
    const float* __restrict__ bqkv,
    unsigned short* __restrict__ qbf, unsigned short* __restrict__ kbf,
    unsigned short* __restrict__ vt,
    const float* __restrict__ xavg, const float* __restrict__ Wqkv,
    float* __restrict__ qavg, float* __restrict__ kavg) {
  __shared__ unsigned short SMEM[2 * 128 * 32];   // 16 KB, carved per path
  const int gid = blockIdx.x;
  const int tid = threadIdx.x;
  if (gid < 768) {
    unsigned short* As = SMEM;
    unsigned short* Bs = SMEM + 128 * 32;
    f32x4 acc[4][4] = {};
    const int id = (gid & 7) * 96 + (gid >> 3);   // XCD-chunked swizzle
    const int bn = (id % 12) * 128, bm = (id / 12) * 128;
    mfma_mainloop(xbf, Wt, bm, bn, As, Bs, acc);
    const int lane = tid & 63, wave = tid >> 6;
    const int wr = wave >> 1, wc = wave & 1;
    const int scol = bn + wc * 64;           // 64-aligned -> s,h uniform per wave
    const int s = scol >> 9, h = (scol >> 6) & 7;
    const int b = bm >> 11, t0b = (bm & (T - 1)) + wr * 64;
    const int bh = b * H + h;
    if (s == 2) {
#pragma unroll
      for (int n = 0; n < 4; ++n) {
        const int d = (n * 16 + (lane & 15));
        const float bv = bqkv[scol + n * 16 + (lane & 15)];
#pragma unroll
        for (int m = 0; m < 4; ++m) {
          const int t = t0b + m * 16 + (lane >> 4) * 4;
          ushort4 pk;
          pk.x = f2bf(acc[m][n][0] + bv); pk.y = f2bf(acc[m][n][1] + bv);
          pk.z = f2bf(acc[m][n][2] + bv); pk.w = f2bf(acc[m][n][3] + bv);
          *(ushort4*)&vt[((size_t)bh * Dh + d) * T + t] = pk;
        }
      }
    } else {
      unsigned short* dstbase = ((s == 0) ? qbf : kbf) + (size_t)bh * T * Dh;
      const int g = lane >> 4, i = lane & 3, a = (lane >> 2) & 3;
#pragma unroll
      for (int n = 0; n < 4; ++n) {
        const float bv = bqkv[scol + n * 16 + (lane & 15)];
#pragma unroll
        for (int m = 0; m < 4; ++m) {
          const float v0 = acc[m][n][0] + bv, v1 = acc[m][n][1] + bv;
          const float v2 = acc[m][n][2] + bv, v3 = acc[m][n][3] + bv;
          const unsigned p01 = cvt_pk_bf16(v0, v1);
          const unsigned p23 = cvt_pk_bf16(v2, v3);
          const unsigned u01 = (unsigned)__shfl_xor((int)p01, 1);
          const unsigned u23 = (unsigned)__shfl_xor((int)p23, 1);
          const unsigned A  = (lane & 1) ? ((u01 >> 16) | (p01 & 0xFFFF0000u))
                                         : ((p01 & 0xFFFFu) | (u01 << 16));
          const unsigned Bb = (lane & 1) ? ((u23 >> 16) | (p23 & 0xFFFF0000u))
                                         : ((p23 & 0xFFFFu) | (u23 << 16));
          const unsigned w  = (unsigned)__shfl_xor((int)A, 2);
          const unsigned xw = (unsigned)__shfl_xor((int)Bb, 2);
          uint2 res;
          res.x = (lane & 2) ? xw : A;
          res.y = (lane & 2) ? Bb : w;
          const int t = t0b + m * 16 + 4 * g + i;
          const int d = n * 16 + 4 * a;
          *(uint2*)&dstbase[(size_t)t * Dh + d] = res;
        }
      }
    }
  } else {
    // ---- qkavg path (R6-exact): 32x64 f32 tile, BK=32, 4x2 microtile ----
    float* Asf = (float*)SMEM;            // [32][36] k-major (transposed store)
    float* Bsf = (float*)SMEM + 32 * 36;  // [32][68]
    const int id2 = gid - 768;
    const int bm = (id2 >> 4) * 32, bn = (id2 & 15) * 64;
    const int arow = tid >> 3;            // 0..31
    const int acol = (tid & 7) << 2;      // 0..28
    const int brow = tid >> 4;            // 0..15 (+16)
    const int bcol = (tid & 15) << 2;     // 0..60
    const int tm = (tid >> 5) << 2;       // 0..28
    const int tn = (tid & 31) << 1;       // 0..62
    float acc[4][2] = {};
    for (int k0 = 0; k0 < KD; k0 += 32) {
      const float4 a = *(const float4*)&xavg[(size_t)(bm + arow) * KD + (k0 + acol)];
      Asf[(acol + 0) * 36 + arow] = a.x;
      Asf[(acol + 1) * 36 + arow] = a.y;
      Asf[(acol + 2) * 36 + arow] = a.z;
      Asf[(acol + 3) * 36 + arow] = a.w;
#pragma unroll
      for (int p = 0; p < 2; ++p)
        *(float4*)&Bsf[(brow + 16 * p) * 68 + bcol] =
            *(const float4*)&Wqkv[(size_t)(k0 + brow + 16 * p) * QKV_N + (bn + bcol)];
      __syncthreads();
#pragma unroll
      for (int kk = 0; kk < 32; ++kk) {
        const float4 av = *(const float4*)&Asf[kk * 36 + tm];
        const float2 bv = *(const float2*)&Bsf[kk * 68 + tn];
        const float aa[4] = {av.x, av.y, av.z, av.w};
#pragma unroll
        for (int i = 0; i < 4; ++i) {
          acc[i][0] += aa[i] * bv.x;
          acc[i][1] += aa[i] * bv.y;
        }
      }
      __syncthreads();
    }
#pragma unroll
    for (int i = 0; i < 4; ++i) {
      const int m = bm + tm + i;
      const int b = m >> 7, n = m & (Nr - 1);
#pragma unroll
      for (int j = 0; j < 2; ++j) {
        const int col = bn + tn + j;
        const int half = col >> 9, h = (col >> 6) & 7, d = col & 63;
        float* dst = half ? kavg : qavg;
        dst[(((size_t)b * H + h) * Nr + n) * Dh + d] = acc[i][j] + bqkv[col];
      }
    }
  }
}

// ---------------------------------------------------------------------------
// MFMA block-sparse attention with INLINE top-k (R13 body; NEW wave->region
// mapping: sibling waves handle 4 CONSECUTIVE regions of the same (b,h) for
// L1/L2 locality; XCD chunk from blockIdx only. Bijective over 4096.)
// ---------------------------------------------------------------------------
__global__ __launch_bounds__(256) void attn_mfma_kernel(
    const unsigned short* __restrict__ qbf, const unsigned short* __restrict__ kbf,
    const unsigned short* __restrict__ vt,
    const float* __restrict__ qavg, const float* __restrict__ kavg,
    unsigned short* __restrict__ aoutbf) {
  const int blk = (blockIdx.x & 7) * 512 + (blockIdx.x >> 3) * 4 + (threadIdx.x >> 6);
  const int bh = blk >> 7, n = blk & (Nr - 1);
  const int b = bh >> 3, h = bh & 7;
  const int lane = threadIdx.x & 63;

  // ---- inline top-8 region selection (identical arithmetic to topk_kernel) ----
  const float qv = qavg[(size_t)blk * Dh + lane];
  const float4* k0p = (const float4*)(kavg + ((size_t)bh * Nr + lane) * Dh);
  const float4* k1p = (const float4*)(kavg + ((size_t)bh * Nr + lane + 64) * Dh);
  float d0 = 0.f, d1 = 0.f;
#pragma unroll
  for (int j = 0; j < 16; ++j) {
    const float4 a = k0p[j];
    const float4 bq = k1p[j];
    const float q0 = __shfl(qv, 4 * j + 0);
    const float q1 = __shfl(qv, 4 * j + 1);
    const float q2 = __shfl(qv, 4 * j + 2);
    const float q3 = __shfl(qv, 4 * j + 3);
    d0 += q0 * a.x;  d0 += q1 * a.y;  d0 += q2 * a.z;  d0 += q3 * a.w;
    d1 += q0 * bq.x; d1 += q1 * bq.y; d1 += q2 * bq.z; d1 += q3 * bq.w;
  }
  float v0 = d0, v1 = d1;
  int myidx = 0;
#pragma unroll
  for (int j = 0; j < K; ++j) {
    const unsigned long long c0 =
        ((unsigned long long)fkey(v0) << 32) | (unsigned)(127 - lane);
    const unsigned long long c1 =
        ((unsigned long long)fkey(v1) << 32) | (unsigned)(63 - lane);
    unsigned long long c = (c0 > c1) ? c0 : c1;
#pragma unroll
    for (int off = 1; off < 64; off <<= 1) {
      const unsigned long long o = __shfl_xor(c, off);
      c = (o > c) ? o : c;
    }
    const int idx = 127 - (int)(c & 0xffffffffu);
    if (lane == j) myidx = idx;
    if (idx == lane) v0 = -INFINITY;
    if (idx == lane + 64) v1 = -INFINITY;
  }
  int ridx[8];
#pragma unroll
  for (int j = 0; j < 8; ++j) ridx[j] = __shfl(myidx, j);

  // ---- attention (R10-exact) ----
  const int q = lane & 15, kg = lane >> 4;
  const int kg1 = kg & 1, kgh = kg >> 1;
  const unsigned short* qp = qbf + ((size_t)bh * T + n * R + q) * Dh + kg * 8;
  const bf16x8 qf0 = *(const bf16x8*)(qp);
  const bf16x8 qf1 = *(const bf16x8*)(qp + 32);

  f32x4 s[8];
#pragma unroll
  for (int j = 0; j < 8; ++j) {
    const unsigned short* kp = kbf + ((size_t)bh * T + ridx[j] * R + q) * Dh + kg * 8;
    const bf16x8 kf0 = *(const bf16x8*)(kp);
    const bf16x8 kf1 = *(const bf16x8*)(kp + 32);
    f32x4 acc = {};
    acc = __builtin_amdgcn_mfma_f32_16x16x32_bf16(kf0, qf0, acc, 0, 0, 0);
    acc = __builtin_amdgcn_mfma_f32_16x16x32_bf16(kf1, qf1, acc, 0, 0, 0);
    s[j] = acc;
  }

  float mx = s[0][0];
#pragma unroll
  for (int j = 0; j < 8; ++j)
#pragma unroll
    for (int r = 0; r < 4; ++r) mx = fmaxf(mx, s[j][r]);
  mx = fmaxf(mx, __shfl_xor(mx, 16));
  mx = fmaxf(mx, __shfl_xor(mx, 32));
  float sum = 0.f;
#pragma unroll
  for (int j = 0; j < 8; ++j)
#pragma unroll
    for (int r = 0; r < 4; ++r) {
      const float e = __expf((s[j][r] - mx) * SCALE);
      s[j][r] = e; sum += e;
    }
  sum += __shfl_xor(sum, 16);
  sum += __shfl_xor(sum, 32);

  unsigned pk0[8], pk1[8];
#pragma unroll
  for (int j = 0; j < 8; ++j) {
    pk0[j] = cvt_pk_bf16(s[j][0], s[j][1]);
    pk1[j] = cvt_pk_bf16(s[j][2], s[j][3]);
  }

  const int srcA = kg1 * 32 + q;
  const int srcB = kg1 * 32 + 16 + q;
  f32x4 o[4] = {};
#pragma unroll
  for (int t = 0; t < 4; ++t) {
    const unsigned aa0 = __shfl((int)pk0[2 * t], srcA), aa1 = __shfl((int)pk0[2 * t + 1], srcA);
    const unsigned ab0 = __shfl((int)pk1[2 * t], srcA), ab1 = __shfl((int)pk1[2 * t + 1], srcA);
    const unsigned ba0 = __shfl((int)pk0[2 * t], srcB), ba1 = __shfl((int)pk0[2 * t + 1], srcB);
    const unsigned bb0 = __shfl((int)pk1[2 * t], srcB), bb1 = __shfl((int)pk1[2 * t + 1], srcB);
    union { uint4 u; bf16x8 v; } bu;
    bu.u.x = kgh ? aa1 : aa0;
    bu.u.y = kgh ? ab1 : ab0;
    bu.u.z = kgh ? ba1 : ba0;
    bu.u.w = kgh ? bb1 : bb0;
    const int reg = kgh ? ridx[2 * t + 1] : ridx[2 * t];
    const size_t tok = (size_t)reg * R + kg1 * 8;
#pragma unroll
    for (int dt = 0; dt < 4; ++dt) {
      const bf16x8 af = *(const bf16x8*)(vt + ((size_t)bh * Dh + 16 * dt + q) * T + tok);
      o[dt] = __builtin_amdgcn_mfma_f32_16x16x32_bf16(af, bu.v, o[dt], 0, 0, 0);
    }
  }

  const float inv = 1.0f / sum;
  unsigned short* dst = aoutbf + ((size_t)b * T + n * R + q) * C + h * Dh;
#pragma unroll
  for (int dt = 0; dt < 4; ++dt) {
    const unsigned plo = cvt_pk_bf16(o[dt][0] * inv, o[dt][1] * inv);
    const unsigned phi = cvt_pk_bf16(o[dt][2] * inv, o[dt][3] * inv);
    uint2 st; st.x = plo; st.y = phi;
    *(uint2*)(dst + 16 * dt + kg * 4) = st;
  }
}

// ---------------------------------------------------------------------------
// Output GEMM (R6-exact, 4-wave mainloop, FROZEN).
// ---------------------------------------------------------------------------
__global__ __launch_bounds__(256) void out_gemm_mfma_kernel(
    const unsigned short* __restrict__ Abf, const unsigned short* __restrict__ Wt,
    const float* __restrict__ bias, float* __restrict__ out) {
  __shared__ unsigned short As[128 * 32];
  __shared__ unsigned short Bs[128 * 32];
  f32x4 acc[4][4] = {};
  const int id = (blockIdx.x & 7) * 32 + (blockIdx.x >> 3);
  const int bn = (id & 3) * 128, bm = (id >> 2) * 128;
  mfma_mainloop(Abf, Wt, bm, bn, As, Bs, acc);
  const int lane = threadIdx.x & 63, wave = threadIdx.x >> 6;
  const int wr = wave >> 1, wc = wave & 1;
#pragma unroll
  for (int n = 0; n < 4; ++n) {
    const int col = bn + wc * 64 + n * 16 + (lane & 15);
    const float bv = bias[col];
#pragma unroll
    for (int m = 0; m < 4; ++m) {
      const int row = bm + wr * 64 + m * 16 + (lane >> 4) * 4;
#pragma unroll
      for (int r = 0; r < 4; ++r)
        out[(size_t)(row + r) * C + col] = acc[m][n][r] + bv;
    }
  }
}

extern "C" void kernel_launch(void* const* d_in, const int* in_sizes, int n_in,
                              void* d_out, int out_size, void* d_ws, size_t ws_size,
                              hipStream_t stream) {
  const float* x    = (const float*)d_in[0];
  const float* Wqkv = (const float*)d_in[1];
  const float* bqkv = (const float*)d_in[2];
  const float* Wout = (const float*)d_in[3];
  const float* bout = (const float*)d_in[4];
  float* out = (float*)d_out;

  float* ws = (float*)d_ws;
  const size_t bhtd = (size_t)B * H * T * Dh;     // 4,194,304
  const size_t navg = (size_t)B * H * Nr * Dh;    // 262,144
  float* qavg = ws;
  float* kavg = qavg + navg;
  float* xavg = kavg + navg;                       // B*Nr*C
  unsigned short* qbf    = (unsigned short*)(xavg + navg);
  unsigned short* kbf    = qbf + bhtd;
  unsigned short* vt     = kbf + bhtd;
  unsigned short* xbf    = vt + bhtd;
  unsigned short* wqkvt  = xbf + bhtd;
  unsigned short* woutt  = wqkvt + (size_t)QKV_N * KD;
  unsigned short* aoutbf = woutt + (size_t)C * KD;

  prep_combo_kernel<<<1280, 256, 0, stream>>>(x, Wqkv, Wout, xbf, xavg, wqkvt, woutt);
  mega_gemm_kernel<<<1024, 256, 0, stream>>>(xbf, wqkvt, bqkv, qbf, kbf, vt,
                                             xavg, Wqkv, qavg, kavg);
  attn_mfma_kernel<<<B * H * Nr / 4, 256, 0, stream>>>(qbf, kbf, vt, qavg, kavg, aoutbf);
  out_gemm_mfma_kernel<<<C / 128 * (BT / 128), 256, 0, stream>>>(aoutbf, woutt, bout, out);
}